// Round 2
// baseline (383.251 us; speedup 1.0000x reference)
//
#include <hip/hip_runtime.h>
#include <hip/hip_bf16.h>
#include <stdint.h>

// Problem constants
#define NB 16       // batch
#define NC 128      // C_in == C_out
#define NK 128      // modes
#define NSP 16384   // spatial N
#define SPLIT 32    // split-K chunks per batch for GEMM1
#define CHUNK 512   // NSP / SPLIT
#define BK 64       // reduction tile for GEMM1

typedef float f32x4 __attribute__((ext_vector_type(4)));
typedef __bf16 bf16x8 __attribute__((ext_vector_type(8)));

__device__ __forceinline__ unsigned short f32_to_bf16(float a) {
  unsigned int u = __float_as_uint(a);
  return (unsigned short)((u + 0x7fffu + ((u >> 16) & 1u)) >> 16);
}

__device__ __forceinline__ unsigned int pack_bf16(float a, float b) {
  unsigned int ua = __float_as_uint(a);
  unsigned int ub = __float_as_uint(b);
  ua = (ua + 0x7fffu + ((ua >> 16) & 1u)) >> 16;
  ub = (ub + 0x7fffu + ((ub >> 16) & 1u)) & 0xffff0000u;
  return ua | ub;
}

// ---------------------------------------------------------------------------
// k0a: wbases (NSP x NK) f32  ->  wbT (NK x NSP) bf16   (LDS tile transpose)
__global__ void k0a_transpose(const float* __restrict__ wb,
                              unsigned short* __restrict__ wbT) {
  __shared__ float tile[32][33];
  int kt = (blockIdx.x & 3) * 32;
  int nt = (blockIdx.x >> 2) * 32;
  int tx = threadIdx.x & 31;
  int ty = threadIdx.x >> 5;  // 0..7
#pragma unroll
  for (int i = 0; i < 32; i += 8)
    tile[ty + i][tx] = wb[(size_t)(nt + ty + i) * NK + kt + tx];
  __syncthreads();
#pragma unroll
  for (int i = 0; i < 32; i += 8)
    wbT[(size_t)(kt + ty + i) * NSP + nt + tx] = f32_to_bf16(tile[tx][ty + i]);
}

// ---------------------------------------------------------------------------
// k0b: bases (NSP x NK) f32 -> bf16, same layout
__global__ void k0b_convert(const float* __restrict__ bases,
                            unsigned short* __restrict__ bb) {
  int i = blockIdx.x * 256 + threadIdx.x;  // 524288 float4s = 2M floats
  if (i >= (NSP * NK) / 4) return;
  float4 v = ((const float4*)bases)[i];
  uint2 o;
  o.x = pack_bf16(v.x, v.y);
  o.y = pack_bf16(v.z, v.w);
  ((uint2*)bb)[i] = o;
}

// ---------------------------------------------------------------------------
// k1: split-K GEMM1.  Per block: b = blk/SPLIT, n-chunk = blk%SPLIT.
// Computes partial x_co[b][c][k] over its 512-wide n-range, 128x128 output,
// 4 waves each own a 64x64 quadrant (4x4 tiles of 16x16x32_bf16).
// LDS is fragment-ordered: 16B chunk index = (s*4+q)*128 + row, where the
// chunk holds reduction elements n_local = s*32 + q*8 .. +8 for that row.
__global__ __launch_bounds__(256, 2)
void k1_proj(const float* __restrict__ x, const unsigned short* __restrict__ wbT,
             float* __restrict__ part) {
  int blk = blockIdx.x;
  int b = blk / SPLIT;
  int chunk = blk % SPLIT;
  int n0 = chunk * CHUNK;
  __shared__ unsigned short ldsA[8 * 128 * 8];  // 16 KB
  __shared__ unsigned short ldsB[8 * 128 * 8];  // 16 KB
  int tid = threadIdx.x;
  int lane = tid & 63;
  int wave = tid >> 6;
  int cb = (wave & 1) * 64;   // c quadrant
  int kb = (wave >> 1) * 64;  // k-mode quadrant
  int r = lane & 15;
  int q = lane >> 4;

  f32x4 acc[4][4];
#pragma unroll
  for (int t = 0; t < 4; ++t)
#pragma unroll
    for (int u = 0; u < 4; ++u) acc[t][u] = (f32x4){0.f, 0.f, 0.f, 0.f};

  // staging: thread -> (row = tid/2, half = tid&1 covering 32 reduction elems)
  int c = tid >> 1;
  int hf = tid & 1;
  const float* xp = x + ((size_t)(b * NC + c)) * NSP + n0 + hf * 32;
  const unsigned short* wp = wbT + (size_t)c * NSP + n0 + hf * 32;
  int sbase = hf * 4 * 128 + c;  // chunk index for q2 = 0

  uint4* wA = (uint4*)ldsA;
  uint4* wB = (uint4*)ldsB;
  const bf16x8* pA = (const bf16x8*)ldsA;
  const bf16x8* pB = (const bf16x8*)ldsB;

  for (int it = 0; it < CHUNK / BK; ++it) {  // 8 iterations
    const float4* px4 = (const float4*)(xp + it * BK);
    const uint4* pw4 = (const uint4*)(wp + it * BK);
#pragma unroll
    for (int q2 = 0; q2 < 4; ++q2) {
      float4 a0 = px4[2 * q2];
      float4 a1 = px4[2 * q2 + 1];
      uint4 u;
      u.x = pack_bf16(a0.x, a0.y);
      u.y = pack_bf16(a0.z, a0.w);
      u.z = pack_bf16(a1.x, a1.y);
      u.w = pack_bf16(a1.z, a1.w);
      wA[sbase + q2 * 128] = u;
      wB[sbase + q2 * 128] = pw4[q2];  // already bf16
    }
    __syncthreads();
#pragma unroll
    for (int s = 0; s < 2; ++s) {
      bf16x8 af[4], bfr[4];
#pragma unroll
      for (int t = 0; t < 4; ++t) af[t] = pA[(s * 4 + q) * 128 + cb + 16 * t + r];
#pragma unroll
      for (int u = 0; u < 4; ++u) bfr[u] = pB[(s * 4 + q) * 128 + kb + 16 * u + r];
#pragma unroll
      for (int t = 0; t < 4; ++t)
#pragma unroll
        for (int u = 0; u < 4; ++u)
          acc[t][u] = __builtin_amdgcn_mfma_f32_16x16x32_bf16(af[t], bfr[u],
                                                              acc[t][u], 0, 0, 0);
    }
    __syncthreads();
  }

  // C/D layout: col = lane&15, row = (lane>>4)*4 + reg  [m89-verified]
  float* pp = part + (size_t)blk * (NC * NK);
  int rq = q * 4;
#pragma unroll
  for (int t = 0; t < 4; ++t)
#pragma unroll
    for (int u = 0; u < 4; ++u)
#pragma unroll
      for (int v = 0; v < 4; ++v)
        pp[(cb + 16 * t + rq + v) * NK + kb + 16 * u + r] = acc[t][u][v];
}

// ---------------------------------------------------------------------------
// k1b: reduce SPLIT partials -> x_co fp32 (16 x 128 x 128)
__global__ void k1b_reduce(const float* __restrict__ part,
                           float* __restrict__ x_co) {
  int idx = blockIdx.x * 256 + threadIdx.x;
  for (int e = idx; e < NB * NC * NK; e += 256 * 256) {
    int b = e >> 14;
    int ik = e & 16383;
    const float* p = part + (size_t)b * SPLIT * (NC * NK) + ik;
    float s = 0.f;
#pragma unroll
    for (int c = 0; c < SPLIT; ++c) s += p[(size_t)c * (NC * NK)];
    x_co[e] = s;
  }
}

// ---------------------------------------------------------------------------
// k2: per-mode channel mix. Block = (b, o), lanes = k (128). Fully coalesced:
// x_co[b][i][:] and W[i][o][:] rows are contiguous in k.
__global__ __launch_bounds__(128)
void k2_mix(const float* __restrict__ x_co, const float* __restrict__ W,
            unsigned short* __restrict__ xhat_bf) {
  int b = blockIdx.x >> 7;
  int o = blockIdx.x & 127;
  int k = threadIdx.x;
  const float* xc = x_co + (size_t)b * NC * NK + k;
  const float* wp = W + (size_t)o * NK + k;
  float acc = 0.f;
#pragma unroll 4
  for (int i = 0; i < NC; ++i)
    acc += xc[(size_t)i * NK] * wp[(size_t)i * (NC * NK)];
  xhat_bf[((size_t)b * NC + o) * NK + k] = f32_to_bf16(acc);
}

// ---------------------------------------------------------------------------
// k3: reconstruct. out (2048 x NSP) = xhat (2048 x 128) @ bases^T (128 x NSP).
// Block tile 128(mo) x 128(n), K=128 one-shot. Same fragment-ordered LDS,
// s now spans 0..3 (K=128 = 4 steps of 32).
__global__ __launch_bounds__(256, 2)
void k3_recon(const unsigned short* __restrict__ xhat_bf,
              const unsigned short* __restrict__ bases_bf,
              float* __restrict__ out) {
  int blk = blockIdx.x;
  int mo0 = (blk & 15) * 128;   // 16 mo-tiles; consecutive blocks share n-tile
  int n0 = (blk >> 4) * 128;    // 128 n-tiles
  __shared__ unsigned short ldsA[16 * 128 * 8];  // 32 KB
  __shared__ unsigned short ldsB[16 * 128 * 8];  // 32 KB
  int tid = threadIdx.x;
  int lane = tid & 63;
  int wave = tid >> 6;
  int mb = (wave & 1) * 64;
  int nb = (wave >> 1) * 64;
  int r = lane & 15;
  int q = lane >> 4;

  int row = tid >> 1;
  int hf = tid & 1;
  const uint4* pa4 = (const uint4*)(xhat_bf + (size_t)(mo0 + row) * NK + hf * 64);
  const uint4* pb4 = (const uint4*)(bases_bf + (size_t)(n0 + row) * NK + hf * 64);
  uint4* wA = (uint4*)ldsA;
  uint4* wB = (uint4*)ldsB;
#pragma unroll
  for (int j = 0; j < 8; ++j) {  // chunk idx = (s*4+q)*128 + row = (hf*8+j)*128 + row
    wA[(hf * 8 + j) * 128 + row] = pa4[j];
    wB[(hf * 8 + j) * 128 + row] = pb4[j];
  }
  __syncthreads();

  const bf16x8* pA = (const bf16x8*)ldsA;
  const bf16x8* pB = (const bf16x8*)ldsB;
  f32x4 acc[4][4];
#pragma unroll
  for (int t = 0; t < 4; ++t)
#pragma unroll
    for (int u = 0; u < 4; ++u) acc[t][u] = (f32x4){0.f, 0.f, 0.f, 0.f};

#pragma unroll
  for (int s = 0; s < 4; ++s) {
    bf16x8 af[4], bfr[4];
#pragma unroll
    for (int t = 0; t < 4; ++t) af[t] = pA[(s * 4 + q) * 128 + mb + 16 * t + r];
#pragma unroll
    for (int u = 0; u < 4; ++u) bfr[u] = pB[(s * 4 + q) * 128 + nb + 16 * u + r];
#pragma unroll
    for (int t = 0; t < 4; ++t)
#pragma unroll
      for (int u = 0; u < 4; ++u)
        acc[t][u] = __builtin_amdgcn_mfma_f32_16x16x32_bf16(af[t], bfr[u],
                                                            acc[t][u], 0, 0, 0);
  }

  int rq = q * 4;
#pragma unroll
  for (int t = 0; t < 4; ++t)
#pragma unroll
    for (int u = 0; u < 4; ++u)
#pragma unroll
      for (int v = 0; v < 4; ++v)
        out[(size_t)(mo0 + mb + 16 * t + rq + v) * NSP + n0 + nb + 16 * u + r] =
            acc[t][u][v];
}

// ---------------------------------------------------------------------------
extern "C" void kernel_launch(void* const* d_in, const int* in_sizes, int n_in,
                              void* d_out, int out_size, void* d_ws, size_t ws_size,
                              hipStream_t stream) {
  const float* x = (const float*)d_in[0];       // (16,128,16384)
  const float* wbases = (const float*)d_in[1];  // (16384,128)
  const float* bases = (const float*)d_in[2];   // (16384,128)
  const float* W = (const float*)d_in[3];       // (128,128,128)
  float* out = (float*)d_out;                   // (16,128,16384)

  char* ws = (char*)d_ws;
  // ws layout (MB offsets): wbT 0..4 | bases_bf 4..8 | part 8..40 | x_co 40..41 | xhat 41..41.5
  if (ws_size < ((size_t)42 << 20)) return;  // insufficient scratch -> clean fail
  unsigned short* wbT = (unsigned short*)(ws);
  unsigned short* bases_bf = (unsigned short*)(ws + ((size_t)4 << 20));
  float* part = (float*)(ws + ((size_t)8 << 20));
  float* x_co = (float*)(ws + ((size_t)40 << 20));
  unsigned short* xhat_bf = (unsigned short*)(ws + ((size_t)41 << 20));

  k0a_transpose<<<2048, 256, 0, stream>>>(wbases, wbT);
  k0b_convert<<<2048, 256, 0, stream>>>(bases, bases_bf);
  k1_proj<<<NB * SPLIT, 256, 0, stream>>>(x, wbT, part);
  k1b_reduce<<<256, 256, 0, stream>>>(part, x_co);
  k2_mix<<<NB * NC, 128, 0, stream>>>(x_co, W, xhat_bf);
  k3_recon<<<2048, 256, 0, stream>>>(xhat_bf, bases_bf, out);
}

// Round 3
// 299.317 us; speedup vs baseline: 1.2804x; 1.2804x over previous
//
#include <hip/hip_runtime.h>
#include <hip/hip_bf16.h>
#include <stdint.h>

// Problem constants
#define NB 16       // batch
#define NC 128      // C_in == C_out
#define NK 128      // modes
#define NSP 16384   // spatial N
#define SPLIT 32    // split-K chunks per batch for GEMM1
#define CHUNK 512   // NSP / SPLIT
#define BK 64       // reduction tile for GEMM1

typedef float f32x4 __attribute__((ext_vector_type(4)));
typedef __bf16 bf16x8 __attribute__((ext_vector_type(8)));

__device__ __forceinline__ unsigned short f32_to_bf16(float a) {
  unsigned int u = __float_as_uint(a);
  return (unsigned short)((u + 0x7fffu + ((u >> 16) & 1u)) >> 16);
}

__device__ __forceinline__ unsigned int pack_bf16(float a, float b) {
  unsigned int ua = __float_as_uint(a);
  unsigned int ub = __float_as_uint(b);
  ua = (ua + 0x7fffu + ((ua >> 16) & 1u)) >> 16;
  ub = (ub + 0x7fffu + ((ub >> 16) & 1u)) & 0xffff0000u;
  return ua | ub;
}

// async global->LDS copy, 16 B per lane; LDS dst = base + lane*16 (wave-uniform base)
__device__ __forceinline__ void gl_lds16(const void* g, void* l) {
  __builtin_amdgcn_global_load_lds(
      (const __attribute__((address_space(1))) unsigned int*)g,
      (__attribute__((address_space(3))) unsigned int*)l, 16, 0, 0);
}

// ---------------------------------------------------------------------------
// k0a: wbases (NSP x NK) f32  ->  wbT (NK x NSP) bf16   (LDS tile transpose)
__global__ void k0a_transpose(const float* __restrict__ wb,
                              unsigned short* __restrict__ wbT) {
  __shared__ float tile[32][33];
  int kt = (blockIdx.x & 3) * 32;
  int nt = (blockIdx.x >> 2) * 32;
  int tx = threadIdx.x & 31;
  int ty = threadIdx.x >> 5;  // 0..7
#pragma unroll
  for (int i = 0; i < 32; i += 8)
    tile[ty + i][tx] = wb[(size_t)(nt + ty + i) * NK + kt + tx];
  __syncthreads();
#pragma unroll
  for (int i = 0; i < 32; i += 8)
    wbT[(size_t)(kt + ty + i) * NSP + nt + tx] = f32_to_bf16(tile[tx][ty + i]);
}

// ---------------------------------------------------------------------------
// k0b: bases (NSP x NK) f32 -> bf16, same layout
__global__ void k0b_convert(const float* __restrict__ bases,
                            unsigned short* __restrict__ bb) {
  int i = blockIdx.x * 256 + threadIdx.x;
  if (i >= (NSP * NK) / 4) return;
  float4 v = ((const float4*)bases)[i];
  uint2 o;
  o.x = pack_bf16(v.x, v.y);
  o.y = pack_bf16(v.z, v.w);
  ((uint2*)bb)[i] = o;
}

// ---------------------------------------------------------------------------
// k1 v2: split-K GEMM1. Grid 512 = (b, chunk); 512 threads = 8 waves.
// Output 128c x 128k per block; wave tile 64c x 32k (4x2 of 16x16x32).
// x staged via full-line wave-contiguous float4 loads + bf16 pack into
// fragment-ordered ldsA (chunk g*128+row holds n = g*8..g*8+8 of row).
// wbT staged via async global_load_lds into row-major ldsB
// (128 rows x 128 B, +16 B pad per 1 KB copy instruction).
__global__ __launch_bounds__(512, 4)
void k1_proj(const float* __restrict__ x, const unsigned short* __restrict__ wbT,
             float* __restrict__ part) {
  int blk = blockIdx.x;
  int b = blk >> 5;      // / SPLIT
  int chunk = blk & 31;  // % SPLIT
  int n0 = chunk * CHUNK;
  __shared__ unsigned short ldsA[8 * 128 * 8];  // 16 KB fragment-ordered (x, bf16)
  __shared__ unsigned short ldsB[8320];         // 16.25 KB row-major+pad (wbT)
  int tid = threadIdx.x;
  int lane = tid & 63;
  int wave = tid >> 6;        // 0..7
  int cb = (wave & 1) * 64;   // c quadrant (with t: 4 tiles of 16)
  int kb = (wave >> 1) * 32;  // k-mode block (with u: 2 tiles of 16)
  int r = lane & 15;
  int q = lane >> 4;

  f32x4 acc[4][2];
#pragma unroll
  for (int t = 0; t < 4; ++t)
#pragma unroll
    for (int u = 0; u < 2; ++u) acc[t][u] = (f32x4){0.f, 0.f, 0.f, 0.f};

  // x staging: thread -> (g = tid&7 covering n_local g*8..+8, row0 = tid>>3)
  int g = tid & 7;
  int row0 = tid >> 3;  // 0..63, +64 on round 2
  const float* xbase = x + (size_t)(b * NC) * NSP + n0 + g * 8;
  uint4* wA = (uint4*)ldsA;
  const bf16x8* pA = (const bf16x8*)ldsA;

  // wbT copy: instr i = wave*2+j covers rows 8i..8i+7; lane -> row 8i+(lane>>3),
  // col (lane&7)*8 ; LDS dst = ldsB + i*1040 + lane*16 (row-major, 128 B rows)
  const unsigned short* wsrc =
      wbT + n0 + (size_t)(lane >> 3) * NSP + (lane & 7) * 8;

  for (int it = 0; it < CHUNK / BK; ++it) {  // 8 iterations
#pragma unroll
    for (int j = 0; j < 2; ++j) {
      int i = wave * 2 + j;
      gl_lds16(wsrc + (size_t)(i * 8) * NSP + it * BK, (char*)ldsB + i * 1040);
    }
#pragma unroll
    for (int jj = 0; jj < 2; ++jj) {
      int row = row0 + jj * 64;
      const float4* p = (const float4*)(xbase + (size_t)row * NSP + it * BK);
      float4 a0 = p[0];
      float4 a1 = p[1];
      uint4 u;
      u.x = pack_bf16(a0.x, a0.y);
      u.y = pack_bf16(a0.z, a0.w);
      u.z = pack_bf16(a1.x, a1.y);
      u.w = pack_bf16(a1.z, a1.w);
      wA[g * 128 + row] = u;
    }
    __syncthreads();  // drains global_load_lds (vmcnt) + LDS writes
#pragma unroll
    for (int s = 0; s < 2; ++s) {
      bf16x8 af[4], bf[2];
#pragma unroll
      for (int t = 0; t < 4; ++t) af[t] = pA[(s * 4 + q) * 128 + cb + 16 * t + r];
#pragma unroll
      for (int u = 0; u < 2; ++u) {
        int rw = kb + 16 * u + r;
        bf[u] = *(const bf16x8*)((const char*)ldsB + rw * 128 + (rw >> 3) * 16 +
                                 s * 64 + q * 16);
      }
#pragma unroll
      for (int t = 0; t < 4; ++t)
#pragma unroll
        for (int u = 0; u < 2; ++u)
          acc[t][u] = __builtin_amdgcn_mfma_f32_16x16x32_bf16(af[t], bf[u],
                                                              acc[t][u], 0, 0, 0);
    }
    __syncthreads();
  }

  // C/D layout: col = lane&15, row = (lane>>4)*4 + reg  [m89-verified]
  float* pp = part + (size_t)blk * (NC * NK);
  int rq = q * 4;
#pragma unroll
  for (int t = 0; t < 4; ++t)
#pragma unroll
    for (int u = 0; u < 2; ++u)
#pragma unroll
      for (int v = 0; v < 4; ++v)
        pp[(cb + 16 * t + rq + v) * NK + kb + 16 * u + r] = acc[t][u][v];
}

// ---------------------------------------------------------------------------
// k1b v2: reduce SPLIT partials -> x_co fp32. float2-vectorized, grid 512.
__global__ __launch_bounds__(256)
void k1b_reduce(const float* __restrict__ part, float* __restrict__ x_co) {
  int idx = blockIdx.x * 256 + threadIdx.x;  // 131072 float2 sites
  int b = idx >> 13;                         // / (NC*NK/2)
  int r2 = idx & 8191;
  const float2* p = (const float2*)(part + (size_t)b * SPLIT * (NC * NK)) + r2;
  float2 s = {0.f, 0.f};
#pragma unroll
  for (int c = 0; c < SPLIT; ++c) {
    float2 v = p[(size_t)c * (NC * NK / 2)];
    s.x += v.x;
    s.y += v.y;
  }
  ((float2*)x_co)[idx] = s;
}

// ---------------------------------------------------------------------------
// k2: per-mode channel mix. Block = (b, o), lanes = k (128). Fully coalesced.
__global__ __launch_bounds__(128)
void k2_mix(const float* __restrict__ x_co, const float* __restrict__ W,
            unsigned short* __restrict__ xhat_bf) {
  int b = blockIdx.x >> 7;
  int o = blockIdx.x & 127;
  int k = threadIdx.x;
  const float* xc = x_co + (size_t)b * NC * NK + k;
  const float* wp = W + (size_t)o * NK + k;
  float acc = 0.f;
#pragma unroll 4
  for (int i = 0; i < NC; ++i)
    acc += xc[(size_t)i * NK] * wp[(size_t)i * (NC * NK)];
  xhat_bf[((size_t)b * NC + o) * NK + k] = f32_to_bf16(acc);
}

// ---------------------------------------------------------------------------
// k3 v2: out (2048 x NSP) = xhat (2048 x 128) @ bases^T. Grid 512 =
// 16 mo-tiles x 32 n-chunks of 512. A-fragments in registers; B (128 rows x
// 128 k bf16 = 32 KB +pad) double-buffered via async global_load_lds so the
// prefetch overlaps MFMA + the 256 KB/block store stream.
__global__ __launch_bounds__(256, 2)
void k3_recon(const unsigned short* __restrict__ xhat_bf,
              const unsigned short* __restrict__ bases_bf,
              float* __restrict__ out) {
  int blk = blockIdx.x;
  int mo0 = (blk & 15) * 128;
  int n0 = (blk >> 4) * 512;
  __shared__ unsigned short ldsB[2][16640];  // 2 x 33280 B (1040 B per 4 rows)
  int tid = threadIdx.x;
  int lane = tid & 63;
  int wave = tid >> 6;  // 0..3
  int mb = (wave & 1) * 64;
  int nb = (wave >> 1) * 64;
  int r = lane & 15;
  int q = lane >> 4;

  // A fragments: rows mo0+mb+16t+r, k = s*32+q*8  (16 x 16 B loads, L2/L3-hot)
  bf16x8 af[4][4];
#pragma unroll
  for (int t = 0; t < 4; ++t)
#pragma unroll
    for (int s = 0; s < 4; ++s)
      af[t][s] = *(const bf16x8*)(xhat_bf +
                                  (size_t)(mo0 + mb + 16 * t + r) * NK +
                                  s * 32 + q * 8);

  // B copy: instr i = wave*8+jj covers rows 4i..4i+3; lane -> row 4i+(lane>>4),
  // col (lane&15)*8 ; dst = buf + i*1040 + lane*16 (256 B rows, 16 B pad/KB)
  const unsigned short* bsrc =
      bases_bf + ((size_t)n0 + (lane >> 4)) * NK + (lane & 15) * 8;

#pragma unroll
  for (int jj = 0; jj < 8; ++jj) {
    int i = wave * 8 + jj;
    gl_lds16(bsrc + (size_t)(i * 4) * NK, (char*)ldsB[0] + i * 1040);
  }

  for (int sub = 0; sub < 4; ++sub) {
    __syncthreads();  // prefetch for this sub-tile complete
    int cur = sub & 1;
    if (sub < 3) {
#pragma unroll
      for (int jj = 0; jj < 8; ++jj) {
        int i = wave * 8 + jj;
        gl_lds16(bsrc + (size_t)((sub + 1) * 128 + i * 4) * NK,
                 (char*)ldsB[cur ^ 1] + i * 1040);
      }
    }
    const char* bbuf = (const char*)ldsB[cur];
    f32x4 acc[4][4];
#pragma unroll
    for (int t = 0; t < 4; ++t)
#pragma unroll
      for (int u = 0; u < 4; ++u) acc[t][u] = (f32x4){0.f, 0.f, 0.f, 0.f};
#pragma unroll
    for (int s = 0; s < 4; ++s) {
      bf16x8 bf[4];
#pragma unroll
      for (int u = 0; u < 4; ++u) {
        int rw = nb + 16 * u + r;
        bf[u] = *(const bf16x8*)(bbuf + rw * 256 + (rw >> 2) * 16 + s * 64 +
                                 q * 16);
      }
#pragma unroll
      for (int t = 0; t < 4; ++t)
#pragma unroll
        for (int u = 0; u < 4; ++u)
          acc[t][u] = __builtin_amdgcn_mfma_f32_16x16x32_bf16(af[t][s], bf[u],
                                                              acc[t][u], 0, 0, 0);
    }
    int rq = q * 4;
#pragma unroll
    for (int t = 0; t < 4; ++t)
#pragma unroll
      for (int u = 0; u < 4; ++u)
#pragma unroll
        for (int v = 0; v < 4; ++v)
          out[(size_t)(mo0 + mb + 16 * t + rq + v) * NSP + n0 + sub * 128 +
              nb + 16 * u + r] = acc[t][u][v];
  }
}

// ---------------------------------------------------------------------------
extern "C" void kernel_launch(void* const* d_in, const int* in_sizes, int n_in,
                              void* d_out, int out_size, void* d_ws, size_t ws_size,
                              hipStream_t stream) {
  const float* x = (const float*)d_in[0];       // (16,128,16384)
  const float* wbases = (const float*)d_in[1];  // (16384,128)
  const float* bases = (const float*)d_in[2];   // (16384,128)
  const float* W = (const float*)d_in[3];       // (128,128,128)
  float* out = (float*)d_out;                   // (16,128,16384)

  char* ws = (char*)d_ws;
  // ws layout (MB): wbT 0..4 | bases_bf 4..8 | part 8..40 | x_co 40..41 | xhat 41..41.5
  if (ws_size < ((size_t)42 << 20)) return;
  unsigned short* wbT = (unsigned short*)(ws);
  unsigned short* bases_bf = (unsigned short*)(ws + ((size_t)4 << 20));
  float* part = (float*)(ws + ((size_t)8 << 20));
  float* x_co = (float*)(ws + ((size_t)40 << 20));
  unsigned short* xhat_bf = (unsigned short*)(ws + ((size_t)41 << 20));

  k0a_transpose<<<2048, 256, 0, stream>>>(wbases, wbT);
  k0b_convert<<<2048, 256, 0, stream>>>(bases, bases_bf);
  k1_proj<<<NB * SPLIT, 512, 0, stream>>>(x, wbT, part);
  k1b_reduce<<<512, 256, 0, stream>>>(part, x_co);
  k2_mix<<<NB * NC, 128, 0, stream>>>(x_co, W, xhat_bf);
  k3_recon<<<512, 256, 0, stream>>>(xhat_bf, bases_bf, out);
}